// Round 4
// baseline (275233.276 us; speedup 1.0000x reference)
//
#include <hip/hip_runtime.h>
#include <stdint.h>

#define T_STEPS 4096
#define IN_DIM  1024
#define H_DIM   2048
#define OUT_DIM 512
#define W_STRIDE 3072        // IN + H
#define NBLK    256          // one persistent block per CU (co-residency safe)
#define NTHR    1024

typedef __attribute__((ext_vector_type(4))) float floatx4;

// XOR swizzle on 16B granules: keeps float4 alignment, spreads bank groups.
__device__ __forceinline__ int swz(int q) { return q ^ ((q >> 3) & 7); }

// ---------------------------------------------------------------------------
// Persistent fused LSTM scan. Block b owns h rows [8b, 8b+8).
// Thread layout: grp = tid>>8 = gate (i,f,o,c); u = tid&255 = col-slice.
// Thread holds W_gate[row0+r][12u .. 12u+12) for r<8 : 96 fp32 VGPRs.
// Per step: xh = concat(x[t], h_t) staged in swizzled LDS; 96 FMAs/thread;
// reduce over 256 threads/gate (wave shfl + LDS); gates by tid<8.
// Epoch barrier: epoch[b] = k  <=>  block b published h_{k-1} (agent scope).
// All cross-block h traffic uses agent-scope atomics (sc-bit cache bypass)
// so freshness never depends on fence/L2-invalidate emission details.
// ---------------------------------------------------------------------------
__global__ __launch_bounds__(NTHR, 4)
void lstm_scan(const float* __restrict__ Wi, const float* __restrict__ Wf,
               const float* __restrict__ Wo, const float* __restrict__ Wc,
               const float* __restrict__ bi, const float* __restrict__ bff,
               const float* __restrict__ bo, const float* __restrict__ bc,
               const float* __restrict__ x,
               float* __restrict__ hbuf,        // [2][H_DIM]
               float* __restrict__ cbuf,        // [H_DIM]
               uint32_t* __restrict__ epoch)    // [NBLK], pre-memset 0
{
  __shared__ float xh[768 * 4];   // 768 granules x 4 floats, XOR-swizzled
  __shared__ float red[16 * 8];   // per-wave partials (16 waves x 8 rows)
  __shared__ float gl[32];        // reduced dots: gate*8 + row
  __shared__ float cl[8];         // cell state for this block's rows

  const int tid  = threadIdx.x;
  const int b    = blockIdx.x;
  const int row0 = b << 3;
  const int grp  = tid >> 8;      // gate id 0..3
  const int u    = tid & 255;     // column slice: cols [12u, 12u+12)

  const float* Wsel = (grp == 0) ? Wi : (grp == 1) ? Wf : (grp == 2) ? Wo : Wc;

  // --- load per-thread weights into registers (one-time, 100 MB chip-wide) ---
  float w[8][12];
  {
    const float* wp = Wsel + (size_t)row0 * W_STRIDE + 12 * u;
#pragma unroll
    for (int r = 0; r < 8; ++r) {
      const float* rp = wp + (size_t)r * W_STRIDE;
#pragma unroll
      for (int j = 0; j < 12; j += 4) {
        const floatx4 v = *(const floatx4*)(rp + j);
        w[r][j] = v.x; w[r][j + 1] = v.y; w[r][j + 2] = v.z; w[r][j + 3] = v.w;
      }
    }
  }

  float bias_i = 0.f, bias_f = 0.f, bias_o = 0.f, bias_c = 0.f;
  if (tid < 8) {
    bias_i = bi[row0 + tid];
    bias_f = bff[row0 + tid];
    bias_o = bo[row0 + tid];
    bias_c = bc[row0 + tid];
    cl[tid] = 0.f;
    // h_0 = 0 into buffer 0 (agent-scope store -> visible at coherent point)
    __hip_atomic_store(&hbuf[row0 + tid], 0.f, __ATOMIC_RELAXED,
                       __HIP_MEMORY_SCOPE_AGENT);
  }
  __syncthreads();
  if (tid == 0) {
    __threadfence();
    __hip_atomic_store(&epoch[b], 1u, __ATOMIC_RELAXED, __HIP_MEMORY_SCOPE_AGENT);
  }

  for (int t = 0; t < T_STEPS; ++t) {
    const float* hin  = hbuf + ((t & 1) ? H_DIM : 0);
    float*       hout = hbuf + ((t & 1) ? 0 : H_DIM);

    // [A] stage x[t] (granules 0..255) — independent of other blocks,
    //     global-load latency overlaps the barrier spin below
    if (tid >= 512 && tid < 768) {
      const int q = tid - 512;
      const floatx4 xv = *(const floatx4*)(x + (size_t)t * IN_DIM + (q << 2));
      *(floatx4*)(xh + (swz(q) << 2)) = xv;
    }
    // [B] wait until every block has published h_t
    if (tid < NBLK) {
      while (__hip_atomic_load(&epoch[tid], __ATOMIC_RELAXED,
                               __HIP_MEMORY_SCOPE_AGENT) < (uint32_t)(t + 1)) {
        __builtin_amdgcn_s_sleep(2);
      }
    }
    __threadfence();
    __syncthreads();

    // [D] stage h_t (granules 256..767) — agent-scope atomic loads bypass
    //     the (non-cross-XCD-coherent) L1/L2, guaranteeing fresh h_t
    if (tid < 512) {
      const int i0 = tid << 2;
      floatx4 hv;
      hv.x = __hip_atomic_load(&hin[i0 + 0], __ATOMIC_RELAXED, __HIP_MEMORY_SCOPE_AGENT);
      hv.y = __hip_atomic_load(&hin[i0 + 1], __ATOMIC_RELAXED, __HIP_MEMORY_SCOPE_AGENT);
      hv.z = __hip_atomic_load(&hin[i0 + 2], __ATOMIC_RELAXED, __HIP_MEMORY_SCOPE_AGENT);
      hv.w = __hip_atomic_load(&hin[i0 + 3], __ATOMIC_RELAXED, __HIP_MEMORY_SCOPE_AGENT);
      *(floatx4*)(xh + (swz(256 + tid) << 2)) = hv;
    }
    __syncthreads();

    // [F] 96 FMAs: acc[r] += W[row0+r][12u+j] * xh[12u+j]
    float acc[8];
#pragma unroll
    for (int r = 0; r < 8; ++r) acc[r] = 0.f;
#pragma unroll
    for (int j3 = 0; j3 < 3; ++j3) {
      const floatx4 v = *(const floatx4*)(xh + (swz(3 * u + j3) << 2));
#pragma unroll
      for (int r = 0; r < 8; ++r) {
        acc[r] = fmaf(w[r][4 * j3 + 0], v.x, acc[r]);
        acc[r] = fmaf(w[r][4 * j3 + 1], v.y, acc[r]);
        acc[r] = fmaf(w[r][4 * j3 + 2], v.z, acc[r]);
        acc[r] = fmaf(w[r][4 * j3 + 3], v.w, acc[r]);
      }
    }

    // [G] wave-level reduction (64 lanes -> 1) for each of the 8 rows
#pragma unroll
    for (int r = 0; r < 8; ++r) {
      float a = acc[r];
      a += __shfl_down(a, 32, 64);
      a += __shfl_down(a, 16, 64);
      a += __shfl_down(a, 8, 64);
      a += __shfl_down(a, 4, 64);
      a += __shfl_down(a, 2, 64);
      a += __shfl_down(a, 1, 64);
      acc[r] = a;
    }
    if ((tid & 63) == 0) {
      const int wv = tid >> 6;
#pragma unroll
      for (int r = 0; r < 8; ++r) red[wv * 8 + r] = acc[r];
    }
    __syncthreads();

    // [I] combine the 4 waves of each gate-group
    if (tid < 32) {
      const int g = tid >> 3, rr = tid & 7;
      gl[tid] = red[(4 * g + 0) * 8 + rr] + red[(4 * g + 1) * 8 + rr] +
                red[(4 * g + 2) * 8 + rr] + red[(4 * g + 3) * 8 + rr];
    }
    __syncthreads();

    // [K] gate nonlinearity + state update
    if (tid < 8) {
      const float pi = gl[tid]      + bias_i;
      const float pf = gl[8 + tid]  + bias_f;
      const float po = gl[16 + tid] + bias_o;
      const float pc = gl[24 + tid] + bias_c;
      const float iv = 1.f / (1.f + __expf(-pi));
      const float fv = 1.f / (1.f + __expf(-pf));
      const float ov = 1.f / (1.f + __expf(-po));
      const float ct = tanhf(pc);
      const float cn = fv * cl[tid] + iv * ct;
      cl[tid] = cn;
      __hip_atomic_store(&hout[row0 + tid], ov * tanhf(cn), __ATOMIC_RELAXED,
                         __HIP_MEMORY_SCOPE_AGENT);
    }
    __syncthreads();
    if (tid == 0) {
      __threadfence();   // release h_{t+1}
      __hip_atomic_store(&epoch[b], (uint32_t)(t + 2), __ATOMIC_RELAXED,
                         __HIP_MEMORY_SCOPE_AGENT);
    }
  }

  if (tid < 8) cbuf[row0 + tid] = cl[tid];
  // final h = h_T is in hbuf[0 .. H_DIM)   (t=4095 odd wrote buffer 0)
}

// ---------------------------------------------------------------------------
// out[0:512] = W2 @ [h; c] + b2   (fp32 in, fp32 out)
// ---------------------------------------------------------------------------
__global__ __launch_bounds__(256)
void final_kernel(const float* __restrict__ W2, const float* __restrict__ b2,
                  const float* __restrict__ hfin, const float* __restrict__ cfin,
                  float* __restrict__ out)
{
  const int wv   = threadIdx.x >> 6;
  const int lane = threadIdx.x & 63;
  const int row  = (blockIdx.x << 2) + wv;
  const float* wr = W2 + (size_t)row * (2 * H_DIM);
  float acc = 0.f;
#pragma unroll 4
  for (int k = lane; k < H_DIM; k += 64) {
    acc = fmaf(wr[k], hfin[k], acc);
    acc = fmaf(wr[H_DIM + k], cfin[k], acc);
  }
#pragma unroll
  for (int off = 32; off > 0; off >>= 1) acc += __shfl_down(acc, off, 64);
  if (lane == 0) out[row] = acc + b2[row];
}

__global__ __launch_bounds__(256)
void copy_h_kernel(const float* __restrict__ hfin, float* __restrict__ out)
{
  const int i = blockIdx.x * 256 + threadIdx.x;
  if (i < H_DIM) out[OUT_DIM + i] = hfin[i];
}

// ---------------------------------------------------------------------------
extern "C" void kernel_launch(void* const* d_in, const int* in_sizes, int n_in,
                              void* d_out, int out_size, void* d_ws, size_t ws_size,
                              hipStream_t stream)
{
  const float* x   = (const float*)d_in[0];
  const float* Wi  = (const float*)d_in[1];
  const float* bi  = (const float*)d_in[2];
  const float* Wf  = (const float*)d_in[3];
  const float* bff = (const float*)d_in[4];
  const float* Wo  = (const float*)d_in[5];
  const float* bo  = (const float*)d_in[6];
  const float* Wc  = (const float*)d_in[7];
  const float* bc  = (const float*)d_in[8];
  const float* W2  = (const float*)d_in[9];
  const float* b2  = (const float*)d_in[10];
  float* out = (float*)d_out;

  // workspace: [hbuf 2*H f32][cbuf H f32][epoch 256 u32]  (~25 KB total)
  char* ws = (char*)d_ws;
  float*    hbuf  = (float*)ws;
  float*    cbuf  = hbuf + 2 * H_DIM;
  uint32_t* epoch = (uint32_t*)(cbuf + H_DIM);

  hipMemsetAsync(epoch, 0, NBLK * sizeof(uint32_t), stream);

  lstm_scan<<<dim3(NBLK), dim3(NTHR), 0, stream>>>(
      Wi, Wf, Wo, Wc, bi, bff, bo, bc, x, hbuf, cbuf, epoch);
  final_kernel<<<dim3(OUT_DIM / 4), 256, 0, stream>>>(W2, b2, hbuf, cbuf, out);
  copy_h_kernel<<<dim3((H_DIM + 255) / 256), 256, 0, stream>>>(hbuf, out);
}

// Round 5
// 35587.286 us; speedup vs baseline: 7.7340x; 7.7340x over previous
//
#include <hip/hip_runtime.h>
#include <stdint.h>

#define T_STEPS 4096
#define IN_DIM  1024
#define H_DIM   2048
#define OUT_DIM 512
#define W_STRIDE 3072        // IN + H
#define NBLK    256          // one persistent block per CU
#define NTHR    1024

typedef __attribute__((ext_vector_type(4))) float floatx4;

// XOR swizzle on 16B granules: keeps float4 alignment, spreads bank groups.
__device__ __forceinline__ int swz(int q) { return q ^ ((q >> 3) & 7); }

// ---------------------------------------------------------------------------
// Persistent fused LSTM scan. Block b owns h rows [8b, 8b+8).
// grp = tid>>8 = gate (i,f,o,c); u = tid&255 = col-slice (12 cols).
// Weights W_gate[row0+r][12u..12u+12), r<8: 24 NAMED floatx4 (96 VGPRs) —
// named vars force SROA promotion (R4's w[8][12] array fell to scratch:
// VGPR_Count=64 + 100 MB/step scratch reload = the 275 ms disaster).
// No __threadfence(): all cross-block traffic is agent-scope (sc1) atomics,
// coherent at MALL; release ordering = s_waitcnt vmcnt(0) before epoch pub.
// ---------------------------------------------------------------------------
#define WDECL(r) floatx4 w##r##a, w##r##b, w##r##c
#define WLOAD(r) do { const float* rp_ = wbase + (size_t)(r) * W_STRIDE;      \
    w##r##a = *(const floatx4*)(rp_);                                         \
    w##r##b = *(const floatx4*)(rp_ + 4);                                     \
    w##r##c = *(const floatx4*)(rp_ + 8); } while (0)
#define FMA4(acc, wq, vq)                                                     \
    acc = fmaf(wq.x, vq.x, acc); acc = fmaf(wq.y, vq.y, acc);                 \
    acc = fmaf(wq.z, vq.z, acc); acc = fmaf(wq.w, vq.w, acc)

__global__ __launch_bounds__(NTHR, 4)
void lstm_scan(const float* __restrict__ Wi, const float* __restrict__ Wf,
               const float* __restrict__ Wo, const float* __restrict__ Wc,
               const float* __restrict__ bi, const float* __restrict__ bff,
               const float* __restrict__ bo, const float* __restrict__ bc,
               const float* __restrict__ x,
               float* __restrict__ hbuf,        // [2][H_DIM]
               float* __restrict__ cbuf,        // [H_DIM]
               uint32_t* __restrict__ epoch)    // [NBLK], pre-memset 0
{
  __shared__ float xh[768 * 4];   // concat(x,h) in XOR-swizzled 16B granules
  __shared__ float red[16 * 8];   // per-wave partials (16 waves x 8 rows)
  __shared__ float cl[8];         // cell state for this block's rows

  const int tid  = threadIdx.x;
  const int b    = blockIdx.x;
  const int row0 = b << 3;
  const int grp  = tid >> 8;      // gate id 0..3
  const int u    = tid & 255;     // column slice: cols [12u, 12u+12)
  const int wv   = tid >> 6;      // wave id 0..15
  const int lane = tid & 63;

  const float* Wsel = (grp == 0) ? Wi : (grp == 1) ? Wf : (grp == 2) ? Wo : Wc;
  const float* wbase = Wsel + (size_t)row0 * W_STRIDE + 12 * u;

  WDECL(0); WDECL(1); WDECL(2); WDECL(3);
  WDECL(4); WDECL(5); WDECL(6); WDECL(7);
  WLOAD(0); WLOAD(1); WLOAD(2); WLOAD(3);
  WLOAD(4); WLOAD(5); WLOAD(6); WLOAD(7);

  float bias_i = 0.f, bias_f = 0.f, bias_o = 0.f, bias_c = 0.f;
  if (tid < 8) {
    bias_i = bi[row0 + tid];
    bias_f = bff[row0 + tid];
    bias_o = bo[row0 + tid];
    bias_c = bc[row0 + tid];
    cl[tid] = 0.f;
    __hip_atomic_store(&hbuf[row0 + tid], 0.f, __ATOMIC_RELAXED,
                       __HIP_MEMORY_SCOPE_AGENT);
  }
  __syncthreads();
  if (tid == 0) {
    __asm__ volatile("s_waitcnt vmcnt(0)" ::: "memory");
    __hip_atomic_store(&epoch[b], 1u, __ATOMIC_RELAXED, __HIP_MEMORY_SCOPE_AGENT);
  }

  // loop-invariant LDS addresses (dword units)
  const int a_v0 = swz(3 * u + 0) << 2;
  const int a_v1 = swz(3 * u + 1) << 2;
  const int a_v2 = swz(3 * u + 2) << 2;
  const int hw0  = (swz(256 + (tid >> 2)) << 2) + (tid & 3);
  const int hw1  = (swz(512 + (tid >> 2)) << 2) + (tid & 3);

  for (int t = 0; t < T_STEPS; ++t) {
    const float* hin  = hbuf + ((t & 1) ? H_DIM : 0);
    float*       hout = hbuf + ((t & 1) ? 0 : H_DIM);

    // [A] stage x[t] (granules 0..255); latency overlaps the spin below
    if (tid >= 512 && tid < 768) {
      const int q = tid - 512;
      const floatx4 xv = *(const floatx4*)(x + (size_t)t * IN_DIM + (q << 2));
      *(floatx4*)(xh + (swz(q) << 2)) = xv;
    }
    // [B] wait until every block has published h_t
    if (tid < NBLK) {
      while (__hip_atomic_load(&epoch[tid], __ATOMIC_RELAXED,
                               __HIP_MEMORY_SCOPE_AGENT) < (uint32_t)(t + 1)) {
        __builtin_amdgcn_s_sleep(1);
      }
    }
    __syncthreads();   // sync1: spin done + prior-step xh reads done

    // [D] stage h_t — coalesced sc1 loads (bypass caches, read MALL)
    {
      const float h0 = __hip_atomic_load(&hin[tid], __ATOMIC_RELAXED,
                                         __HIP_MEMORY_SCOPE_AGENT);
      const float h1 = __hip_atomic_load(&hin[tid + 1024], __ATOMIC_RELAXED,
                                         __HIP_MEMORY_SCOPE_AGENT);
      xh[hw0] = h0;
      xh[hw1] = h1;
    }
    __syncthreads();   // sync2: xh fully staged

    // [F] 96 FMAs against register-resident weights
    float a0 = 0.f, a1 = 0.f, a2 = 0.f, a3 = 0.f,
          a4 = 0.f, a5 = 0.f, a6 = 0.f, a7 = 0.f;
    {
      floatx4 v;
      v = *(const floatx4*)(xh + a_v0);
      FMA4(a0, w0a, v); FMA4(a1, w1a, v); FMA4(a2, w2a, v); FMA4(a3, w3a, v);
      FMA4(a4, w4a, v); FMA4(a5, w5a, v); FMA4(a6, w6a, v); FMA4(a7, w7a, v);
      v = *(const floatx4*)(xh + a_v1);
      FMA4(a0, w0b, v); FMA4(a1, w1b, v); FMA4(a2, w2b, v); FMA4(a3, w3b, v);
      FMA4(a4, w4b, v); FMA4(a5, w5b, v); FMA4(a6, w6b, v); FMA4(a7, w7b, v);
      v = *(const floatx4*)(xh + a_v2);
      FMA4(a0, w0c, v); FMA4(a1, w1c, v); FMA4(a2, w2c, v); FMA4(a3, w3c, v);
      FMA4(a4, w4c, v); FMA4(a5, w5c, v); FMA4(a6, w6c, v); FMA4(a7, w7c, v);
    }

    // [G] wave reduction (64 lanes -> lane 0) for the 8 row-sums
    {
      float arr[8] = {a0, a1, a2, a3, a4, a5, a6, a7};
#pragma unroll
      for (int r = 0; r < 8; ++r) {
        float a = arr[r];
        a += __shfl_down(a, 32, 64);
        a += __shfl_down(a, 16, 64);
        a += __shfl_down(a, 8, 64);
        a += __shfl_down(a, 4, 64);
        a += __shfl_down(a, 2, 64);
        a += __shfl_down(a, 1, 64);
        arr[r] = a;
      }
      if (lane == 0) {
#pragma unroll
        for (int r = 0; r < 8; ++r) red[wv * 8 + r] = arr[r];
      }
    }
    __syncthreads();   // sync3: partials visible

    // [K] combine partials + gates + state update (rows by threads 0..7)
    if (tid < 8) {
      const int rr = tid;
      float pi = bias_i, pf = bias_f, po = bias_o, pc = bias_c;
#pragma unroll
      for (int w = 0; w < 4; ++w) {
        pi += red[(w) * 8 + rr];
        pf += red[(4 + w) * 8 + rr];
        po += red[(8 + w) * 8 + rr];
        pc += red[(12 + w) * 8 + rr];
      }
      const float iv = 1.f / (1.f + __expf(-pi));
      const float fv = 1.f / (1.f + __expf(-pf));
      const float ov = 1.f / (1.f + __expf(-po));
      const float ct = tanhf(pc);
      const float cn = fv * cl[rr] + iv * ct;
      cl[rr] = cn;
      __hip_atomic_store(&hout[row0 + rr], ov * tanhf(cn), __ATOMIC_RELAXED,
                         __HIP_MEMORY_SCOPE_AGENT);
    }
    if (tid == 0) {
      // release: h stores (lanes 0..7, this wave) acked at coherent point
      __asm__ volatile("s_waitcnt vmcnt(0)" ::: "memory");
      __hip_atomic_store(&epoch[b], (uint32_t)(t + 2), __ATOMIC_RELAXED,
                         __HIP_MEMORY_SCOPE_AGENT);
    }
    // no barrier here: next write to xh x-region / red is behind sync1+sync2
  }

  if (tid < 8) cbuf[row0 + tid] = cl[tid];
  // final h = h_T is in hbuf[0 .. H_DIM)   (t=4095 odd wrote buffer 0)
}

// ---------------------------------------------------------------------------
// out[0:512] = W2 @ [h; c] + b2   (fp32 in, fp32 out)
// ---------------------------------------------------------------------------
__global__ __launch_bounds__(256)
void final_kernel(const float* __restrict__ W2, const float* __restrict__ b2,
                  const float* __restrict__ hfin, const float* __restrict__ cfin,
                  float* __restrict__ out)
{
  const int wv   = threadIdx.x >> 6;
  const int lane = threadIdx.x & 63;
  const int row  = (blockIdx.x << 2) + wv;
  const float* wr = W2 + (size_t)row * (2 * H_DIM);
  float acc = 0.f;
#pragma unroll 4
  for (int k = lane; k < H_DIM; k += 64) {
    acc = fmaf(wr[k], hfin[k], acc);
    acc = fmaf(wr[H_DIM + k], cfin[k], acc);
  }
#pragma unroll
  for (int off = 32; off > 0; off >>= 1) acc += __shfl_down(acc, off, 64);
  if (lane == 0) out[row] = acc + b2[row];
}

__global__ __launch_bounds__(256)
void copy_h_kernel(const float* __restrict__ hfin, float* __restrict__ out)
{
  const int i = blockIdx.x * 256 + threadIdx.x;
  if (i < H_DIM) out[OUT_DIM + i] = hfin[i];
}

// ---------------------------------------------------------------------------
extern "C" void kernel_launch(void* const* d_in, const int* in_sizes, int n_in,
                              void* d_out, int out_size, void* d_ws, size_t ws_size,
                              hipStream_t stream)
{
  const float* x   = (const float*)d_in[0];
  const float* Wi  = (const float*)d_in[1];
  const float* bi  = (const float*)d_in[2];
  const float* Wf  = (const float*)d_in[3];
  const float* bff = (const float*)d_in[4];
  const float* Wo  = (const float*)d_in[5];
  const float* bo  = (const float*)d_in[6];
  const float* Wc  = (const float*)d_in[7];
  const float* bc  = (const float*)d_in[8];
  const float* W2  = (const float*)d_in[9];
  const float* b2  = (const float*)d_in[10];
  float* out = (float*)d_out;

  // workspace: [hbuf 2*H f32][cbuf H f32][epoch 256 u32]  (~25 KB total)
  char* ws = (char*)d_ws;
  float*    hbuf  = (float*)ws;
  float*    cbuf  = hbuf + 2 * H_DIM;
  uint32_t* epoch = (uint32_t*)(cbuf + H_DIM);

  hipMemsetAsync(epoch, 0, NBLK * sizeof(uint32_t), stream);

  lstm_scan<<<dim3(NBLK), dim3(NTHR), 0, stream>>>(
      Wi, Wf, Wo, Wc, bi, bff, bo, bc, x, hbuf, cbuf, epoch);
  final_kernel<<<dim3(OUT_DIM / 4), 256, 0, stream>>>(W2, b2, hbuf, cbuf, out);
  copy_h_kernel<<<dim3((H_DIM + 255) / 256), 256, 0, stream>>>(hbuf, out);
}

// Round 6
// 35197.620 us; speedup vs baseline: 7.8197x; 1.0111x over previous
//
#include <hip/hip_runtime.h>
#include <stdint.h>

#define T_STEPS 4096
#define IN_DIM  1024
#define H_DIM   2048
#define OUT_DIM 512
#define W_STRIDE 3072        // IN + H
#define NBLK    256          // one persistent block per CU
#define NTHR    1024

typedef __attribute__((ext_vector_type(4))) float floatx4;

// XOR swizzle on 16B granules: keeps float4 alignment, spreads bank groups.
__device__ __forceinline__ int swz(int q) { return q ^ ((q >> 3) & 7); }

// ---------------------------------------------------------------------------
// Persistent fused LSTM scan. Block b owns h rows [8b, 8b+8).
// grp = tid>>8 = gate (i,f,o,c); u = tid&255 = col-slice (12 cols).
// 96 weights/thread as NAMED SCALARS, pinned in VGPRs via empty asm with
// "+v" constraints executed every iteration — R5's floatx4 version was
// rematerialized into per-step global reloads (VGPR_Count=64, MALL-bound
// 8.65us/step). The asm output is opaque => must stay register-resident.
// Cross-block h/epoch traffic: agent-scope (sc1) atomics, release ordering
// via s_waitcnt vmcnt(0) before epoch publish. No cache-flushing fences.
// ---------------------------------------------------------------------------
#define WROW(r) float w##r##_0, w##r##_1, w##r##_2, w##r##_3, w##r##_4,       \
    w##r##_5, w##r##_6, w##r##_7, w##r##_8, w##r##_9, w##r##_10, w##r##_11
#define WLOAD(r) do { const float* rp_ = wbase + (size_t)(r) * W_STRIDE;      \
    const floatx4 t0_ = *(const floatx4*)(rp_);                               \
    const floatx4 t1_ = *(const floatx4*)(rp_ + 4);                           \
    const floatx4 t2_ = *(const floatx4*)(rp_ + 8);                           \
    w##r##_0 = t0_.x; w##r##_1 = t0_.y; w##r##_2  = t0_.z; w##r##_3  = t0_.w; \
    w##r##_4 = t1_.x; w##r##_5 = t1_.y; w##r##_6  = t1_.z; w##r##_7  = t1_.w; \
    w##r##_8 = t2_.x; w##r##_9 = t2_.y; w##r##_10 = t2_.z; w##r##_11 = t2_.w; \
  } while (0)
#define WPIN(r) __asm__ volatile("" :                                         \
    "+v"(w##r##_0), "+v"(w##r##_1), "+v"(w##r##_2),  "+v"(w##r##_3),          \
    "+v"(w##r##_4), "+v"(w##r##_5), "+v"(w##r##_6),  "+v"(w##r##_7),          \
    "+v"(w##r##_8), "+v"(w##r##_9), "+v"(w##r##_10), "+v"(w##r##_11))
#define FMAA(r, acc) do {                                                     \
    acc = fmaf(w##r##_0, v.x, acc); acc = fmaf(w##r##_1, v.y, acc);           \
    acc = fmaf(w##r##_2, v.z, acc); acc = fmaf(w##r##_3, v.w, acc); } while (0)
#define FMAB(r, acc) do {                                                     \
    acc = fmaf(w##r##_4, v.x, acc); acc = fmaf(w##r##_5, v.y, acc);           \
    acc = fmaf(w##r##_6, v.z, acc); acc = fmaf(w##r##_7, v.w, acc); } while (0)
#define FMAC(r, acc) do {                                                     \
    acc = fmaf(w##r##_8, v.x, acc); acc = fmaf(w##r##_9, v.y, acc);           \
    acc = fmaf(w##r##_10, v.z, acc); acc = fmaf(w##r##_11, v.w, acc); } while (0)

__global__ __launch_bounds__(NTHR, 4)
void lstm_scan(const float* __restrict__ Wi, const float* __restrict__ Wf,
               const float* __restrict__ Wo, const float* __restrict__ Wc,
               const float* __restrict__ bi, const float* __restrict__ bff,
               const float* __restrict__ bo, const float* __restrict__ bc,
               const float* __restrict__ x,
               float* __restrict__ hbuf,        // [2][H_DIM]
               float* __restrict__ cbuf,        // [H_DIM]
               uint32_t* __restrict__ epoch)    // [NBLK], pre-memset 0
{
  __shared__ float xh[768 * 4];   // concat(x,h) in XOR-swizzled 16B granules
  __shared__ float red[16 * 8];   // per-wave partials (16 waves x 8 rows)
  __shared__ float bl[32];        // biases (gate*8+row) — LDS, saves 4 VGPRs
  __shared__ float cl[8];         // cell state for this block's rows

  const int tid  = threadIdx.x;
  const int b    = blockIdx.x;
  const int row0 = b << 3;
  const int grp  = tid >> 8;      // gate id 0..3
  const int u    = tid & 255;     // column slice: cols [12u, 12u+12)
  const int wv   = tid >> 6;      // wave id 0..15
  const int lane = tid & 63;

  const float* Wsel = (grp == 0) ? Wi : (grp == 1) ? Wf : (grp == 2) ? Wo : Wc;
  const float* wbase = Wsel + (size_t)row0 * W_STRIDE + 12 * u;

  WROW(0); WROW(1); WROW(2); WROW(3); WROW(4); WROW(5); WROW(6); WROW(7);
  WLOAD(0); WLOAD(1); WLOAD(2); WLOAD(3);
  WLOAD(4); WLOAD(5); WLOAD(6); WLOAD(7);

  if (tid < 32) {
    const float* Bsel = (tid < 8) ? bi : (tid < 16) ? bff : (tid < 24) ? bo : bc;
    bl[tid] = Bsel[row0 + (tid & 7)];
  }
  if (tid < 8) {
    cl[tid] = 0.f;
    __hip_atomic_store(&hbuf[row0 + tid], 0.f, __ATOMIC_RELAXED,
                       __HIP_MEMORY_SCOPE_AGENT);
  }
  __syncthreads();
  if (tid == 0) {
    __asm__ volatile("s_waitcnt vmcnt(0)" ::: "memory");
    __hip_atomic_store(&epoch[b], 1u, __ATOMIC_RELAXED, __HIP_MEMORY_SCOPE_AGENT);
  }

  // loop-invariant LDS addresses (dword units)
  const int a_v0 = swz(3 * u + 0) << 2;
  const int a_v1 = swz(3 * u + 1) << 2;
  const int a_v2 = swz(3 * u + 2) << 2;
  const int hw0  = (swz(256 + (tid >> 2)) << 2) + (tid & 3);
  const int hw1  = (swz(512 + (tid >> 2)) << 2) + (tid & 3);

  for (int t = 0; t < T_STEPS; ++t) {
    // pin the 96 weight scalars into VGPRs for this iteration (0 instrs)
    WPIN(0); WPIN(1); WPIN(2); WPIN(3); WPIN(4); WPIN(5); WPIN(6); WPIN(7);

    const float* hin  = hbuf + ((t & 1) ? H_DIM : 0);
    float*       hout = hbuf + ((t & 1) ? 0 : H_DIM);

    // [A] stage x[t] (granules 0..255); latency overlaps the spin below
    if (tid >= 512 && tid < 768) {
      const int q = tid - 512;
      const floatx4 xv = *(const floatx4*)(x + ((size_t)t << 10) + (q << 2));
      *(floatx4*)(xh + (swz(q) << 2)) = xv;
    }
    // [B] wait until every block has published h_t
    if (tid < NBLK) {
      while (__hip_atomic_load(&epoch[tid], __ATOMIC_RELAXED,
                               __HIP_MEMORY_SCOPE_AGENT) < (uint32_t)(t + 1)) {
        __builtin_amdgcn_s_sleep(1);
      }
    }
    __syncthreads();   // sync1: spin done + prior-step xh reads done

    // [D] stage h_t — coalesced sc1 loads (bypass caches, read MALL)
    {
      const float h0 = __hip_atomic_load(&hin[tid], __ATOMIC_RELAXED,
                                         __HIP_MEMORY_SCOPE_AGENT);
      const float h1 = __hip_atomic_load(&hin[tid + 1024], __ATOMIC_RELAXED,
                                         __HIP_MEMORY_SCOPE_AGENT);
      xh[hw0] = h0;
      xh[hw1] = h1;
    }
    __syncthreads();   // sync2: xh fully staged

    // [F] 96 FMAs against register-resident weights
    float a0 = 0.f, a1 = 0.f, a2 = 0.f, a3 = 0.f,
          a4 = 0.f, a5 = 0.f, a6 = 0.f, a7 = 0.f;
    {
      floatx4 v;
      v = *(const floatx4*)(xh + a_v0);
      FMAA(0, a0); FMAA(1, a1); FMAA(2, a2); FMAA(3, a3);
      FMAA(4, a4); FMAA(5, a5); FMAA(6, a6); FMAA(7, a7);
      v = *(const floatx4*)(xh + a_v1);
      FMAB(0, a0); FMAB(1, a1); FMAB(2, a2); FMAB(3, a3);
      FMAB(4, a4); FMAB(5, a5); FMAB(6, a6); FMAB(7, a7);
      v = *(const floatx4*)(xh + a_v2);
      FMAC(0, a0); FMAC(1, a1); FMAC(2, a2); FMAC(3, a3);
      FMAC(4, a4); FMAC(5, a5); FMAC(6, a6); FMAC(7, a7);
    }

    // [G] wave reduction (64 lanes -> lane 0) for the 8 row-sums
    {
      float arr[8] = {a0, a1, a2, a3, a4, a5, a6, a7};
#pragma unroll
      for (int r = 0; r < 8; ++r) {
        float a = arr[r];
        a += __shfl_down(a, 32, 64);
        a += __shfl_down(a, 16, 64);
        a += __shfl_down(a, 8, 64);
        a += __shfl_down(a, 4, 64);
        a += __shfl_down(a, 2, 64);
        a += __shfl_down(a, 1, 64);
        arr[r] = a;
      }
      if (lane == 0) {
#pragma unroll
        for (int r = 0; r < 8; ++r) red[wv * 8 + r] = arr[r];
      }
    }
    __syncthreads();   // sync3: partials visible

    // [K] combine partials + gates + state update (rows by threads 0..7)
    if (tid < 8) {
      const int rr = tid;
      float pi = bl[rr], pf = bl[8 + rr], po = bl[16 + rr], pc = bl[24 + rr];
#pragma unroll
      for (int w = 0; w < 4; ++w) {
        pi += red[(w) * 8 + rr];
        pf += red[(4 + w) * 8 + rr];
        po += red[(8 + w) * 8 + rr];
        pc += red[(12 + w) * 8 + rr];
      }
      const float iv = 1.f / (1.f + __expf(-pi));
      const float fv = 1.f / (1.f + __expf(-pf));
      const float ov = 1.f / (1.f + __expf(-po));
      const float ct = tanhf(pc);
      const float cn = fv * cl[rr] + iv * ct;
      cl[rr] = cn;
      __hip_atomic_store(&hout[row0 + rr], ov * tanhf(cn), __ATOMIC_RELAXED,
                         __HIP_MEMORY_SCOPE_AGENT);
    }
    if (tid == 0) {
      // release: h stores (lanes 0..7, this wave) acked at coherent point
      __asm__ volatile("s_waitcnt vmcnt(0)" ::: "memory");
      __hip_atomic_store(&epoch[b], (uint32_t)(t + 2), __ATOMIC_RELAXED,
                         __HIP_MEMORY_SCOPE_AGENT);
    }
    // no barrier here: next writes to xh/red are behind sync1+sync2
  }

  if (tid < 8) cbuf[row0 + tid] = cl[tid];
  // final h = h_T is in hbuf[0 .. H_DIM)   (t=4095 odd wrote buffer 0)
}

// ---------------------------------------------------------------------------
// out[0:512] = W2 @ [h; c] + b2   (fp32 in, fp32 out)
// ---------------------------------------------------------------------------
__global__ __launch_bounds__(256)
void final_kernel(const float* __restrict__ W2, const float* __restrict__ b2,
                  const float* __restrict__ hfin, const float* __restrict__ cfin,
                  float* __restrict__ out)
{
  const int wv   = threadIdx.x >> 6;
  const int lane = threadIdx.x & 63;
  const int row  = (blockIdx.x << 2) + wv;
  const float* wr = W2 + (size_t)row * (2 * H_DIM);
  float acc = 0.f;
#pragma unroll 4
  for (int k = lane; k < H_DIM; k += 64) {
    acc = fmaf(wr[k], hfin[k], acc);
    acc = fmaf(wr[H_DIM + k], cfin[k], acc);
  }
#pragma unroll
  for (int off = 32; off > 0; off >>= 1) acc += __shfl_down(acc, off, 64);
  if (lane == 0) out[row] = acc + b2[row];
}

__global__ __launch_bounds__(256)
void copy_h_kernel(const float* __restrict__ hfin, float* __restrict__ out)
{
  const int i = blockIdx.x * 256 + threadIdx.x;
  if (i < H_DIM) out[OUT_DIM + i] = hfin[i];
}

// ---------------------------------------------------------------------------
extern "C" void kernel_launch(void* const* d_in, const int* in_sizes, int n_in,
                              void* d_out, int out_size, void* d_ws, size_t ws_size,
                              hipStream_t stream)
{
  const float* x   = (const float*)d_in[0];
  const float* Wi  = (const float*)d_in[1];
  const float* bi  = (const float*)d_in[2];
  const float* Wf  = (const float*)d_in[3];
  const float* bff = (const float*)d_in[4];
  const float* Wo  = (const float*)d_in[5];
  const float* bo  = (const float*)d_in[6];
  const float* Wc  = (const float*)d_in[7];
  const float* bc  = (const float*)d_in[8];
  const float* W2  = (const float*)d_in[9];
  const float* b2  = (const float*)d_in[10];
  float* out = (float*)d_out;

  // workspace: [hbuf 2*H f32][cbuf H f32][epoch 256 u32]  (~25 KB total)
  char* ws = (char*)d_ws;
  float*    hbuf  = (float*)ws;
  float*    cbuf  = hbuf + 2 * H_DIM;
  uint32_t* epoch = (uint32_t*)(cbuf + H_DIM);

  hipMemsetAsync(epoch, 0, NBLK * sizeof(uint32_t), stream);

  lstm_scan<<<dim3(NBLK), dim3(NTHR), 0, stream>>>(
      Wi, Wf, Wo, Wc, bi, bff, bo, bc, x, hbuf, cbuf, epoch);
  final_kernel<<<dim3(OUT_DIM / 4), 256, 0, stream>>>(W2, b2, hbuf, cbuf, out);
  copy_h_kernel<<<dim3((H_DIM + 255) / 256), 256, 0, stream>>>(hbuf, out);
}

// Round 7
// 30282.578 us; speedup vs baseline: 9.0888x; 1.1623x over previous
//
#include <hip/hip_runtime.h>
#include <stdint.h>

#define T_STEPS 4096
#define IN_DIM  1024
#define H_DIM   2048
#define OUT_DIM 512
#define W_STRIDE 3072        // IN + H
#define NBLK    256          // one persistent block per CU
#define NTHR    512          // 8 waves/block -> VGPR cap 256 (not 128!)

typedef __attribute__((ext_vector_type(4))) float floatx4;

// XOR swizzle on 16B granules: keeps float4 alignment, spreads bank groups.
__device__ __forceinline__ int swz(int q) { return q ^ ((q >> 3) & 7); }

// ---------------------------------------------------------------------------
// Persistent fused LSTM scan. Block b owns h rows [8b, 8b+8).
// 512 threads: grp = tid>>7 = gate; u = tid&127 = col-slice (24 cols).
// Thread holds W_gate[row0+r][24u..24u+24) for r<8: 192 fp32 = 48 floatx4,
// named scalars. KEY SIZING: 512-thr block = 8 waves = 2 waves/SIMD minimum
// => VGPR cap 256. (R5/R6's 1024-thr blocks capped at 128 < needed ~140 =>
// allocator remat'ed ALL weights as per-step global reloads => 100 MB/step
// from MALL = 8.6us/step. VGPR_Count=64 was the tell.)
// Cross-block h/epoch traffic: agent-scope (sc1) atomics; release ordering
// via s_waitcnt vmcnt(0) before epoch publish. No cache-flushing fences.
// ---------------------------------------------------------------------------
#define WDECL(r) floatx4 w##r##_0, w##r##_1, w##r##_2, w##r##_3, w##r##_4, w##r##_5
#define WLOAD(r) do { const float* rp_ = wbase + (size_t)(r) * W_STRIDE;      \
    w##r##_0 = *(const floatx4*)(rp_ +  0);                                   \
    w##r##_1 = *(const floatx4*)(rp_ +  4);                                   \
    w##r##_2 = *(const floatx4*)(rp_ +  8);                                   \
    w##r##_3 = *(const floatx4*)(rp_ + 12);                                   \
    w##r##_4 = *(const floatx4*)(rp_ + 16);                                   \
    w##r##_5 = *(const floatx4*)(rp_ + 20); } while (0)
#define FMA4(acc, wq) do {                                                    \
    acc = fmaf(wq.x, v.x, acc); acc = fmaf(wq.y, v.y, acc);                   \
    acc = fmaf(wq.z, v.z, acc); acc = fmaf(wq.w, v.w, acc); } while (0)
#define FMAJ(j) do { v = *(const floatx4*)(xh + a_v##j);                      \
    FMA4(ac0, w0_##j); FMA4(ac1, w1_##j); FMA4(ac2, w2_##j);                  \
    FMA4(ac3, w3_##j); FMA4(ac4, w4_##j); FMA4(ac5, w5_##j);                  \
    FMA4(ac6, w6_##j); FMA4(ac7, w7_##j); } while (0)
#define WRED(acc, r) do { float a_ = acc;                                     \
    a_ += __shfl_down(a_, 32, 64); a_ += __shfl_down(a_, 16, 64);             \
    a_ += __shfl_down(a_, 8, 64);  a_ += __shfl_down(a_, 4, 64);              \
    a_ += __shfl_down(a_, 2, 64);  a_ += __shfl_down(a_, 1, 64);              \
    if (lane == 0) red[wv * 8 + (r)] = a_; } while (0)

__global__ __launch_bounds__(NTHR, 2)
void lstm_scan(const float* __restrict__ Wi, const float* __restrict__ Wf,
               const float* __restrict__ Wo, const float* __restrict__ Wc,
               const float* __restrict__ bi, const float* __restrict__ bff,
               const float* __restrict__ bo, const float* __restrict__ bc,
               const float* __restrict__ x,
               float* __restrict__ hbuf,        // [2][H_DIM]
               float* __restrict__ cbuf,        // [H_DIM]
               uint32_t* __restrict__ epoch)    // [NBLK], pre-memset 0
{
  __shared__ float xh[768 * 4];   // concat(x,h) in XOR-swizzled 16B granules
  __shared__ float red[8 * 8];    // per-wave partials (8 waves x 8 rows)
  __shared__ float bl[32];        // biases (gate*8+row)
  __shared__ float cl[8];         // cell state for this block's rows

  const int tid  = threadIdx.x;
  const int b    = blockIdx.x;
  const int row0 = b << 3;
  const int grp  = tid >> 7;      // gate id 0..3
  const int u    = tid & 127;     // column slice: cols [24u, 24u+24)
  const int wv   = tid >> 6;      // wave id 0..7
  const int lane = tid & 63;

  const float* Wsel = (grp == 0) ? Wi : (grp == 1) ? Wf : (grp == 2) ? Wo : Wc;
  const float* wbase = Wsel + (size_t)row0 * W_STRIDE + 24 * u;

  WDECL(0); WDECL(1); WDECL(2); WDECL(3);
  WDECL(4); WDECL(5); WDECL(6); WDECL(7);
  WLOAD(0); WLOAD(1); WLOAD(2); WLOAD(3);
  WLOAD(4); WLOAD(5); WLOAD(6); WLOAD(7);

  if (tid < 32) {
    const float* Bsel = (tid < 8) ? bi : (tid < 16) ? bff : (tid < 24) ? bo : bc;
    bl[tid] = Bsel[row0 + (tid & 7)];
  }
  if (tid < 8) {
    cl[tid] = 0.f;
    __hip_atomic_store(&hbuf[row0 + tid], 0.f, __ATOMIC_RELAXED,
                       __HIP_MEMORY_SCOPE_AGENT);
  }
  __syncthreads();
  if (tid == 0) {
    __asm__ volatile("s_waitcnt vmcnt(0)" ::: "memory");
    __hip_atomic_store(&epoch[b], 1u, __ATOMIC_RELAXED, __HIP_MEMORY_SCOPE_AGENT);
  }

  // loop-invariant LDS addresses (dword units)
  const int a_v0 = swz(6 * u + 0) << 2;
  const int a_v1 = swz(6 * u + 1) << 2;
  const int a_v2 = swz(6 * u + 2) << 2;
  const int a_v3 = swz(6 * u + 3) << 2;
  const int a_v4 = swz(6 * u + 4) << 2;
  const int a_v5 = swz(6 * u + 5) << 2;
  const int hw0 = (swz(256 + (tid >> 2) +   0) << 2) + (tid & 3);
  const int hw1 = (swz(256 + (tid >> 2) + 128) << 2) + (tid & 3);
  const int hw2 = (swz(256 + (tid >> 2) + 256) << 2) + (tid & 3);
  const int hw3 = (swz(256 + (tid >> 2) + 384) << 2) + (tid & 3);

  for (int t = 0; t < T_STEPS; ++t) {
    const float* hin  = hbuf + ((t & 1) ? H_DIM : 0);
    float*       hout = hbuf + ((t & 1) ? 0 : H_DIM);

    // [A] stage x[t] (granules 0..255) on waves 4..7; overlaps spin below
    if (tid >= 256) {
      const int q = tid - 256;
      const floatx4 xv = *(const floatx4*)(x + ((size_t)t << 10) + (q << 2));
      *(floatx4*)(xh + (swz(q) << 2)) = xv;
    }
    // [B] wait until every block has published h_t (waves 0..3)
    if (tid < NBLK) {
      while (__hip_atomic_load(&epoch[tid], __ATOMIC_RELAXED,
                               __HIP_MEMORY_SCOPE_AGENT) < (uint32_t)(t + 1)) {
        __builtin_amdgcn_s_sleep(1);
      }
    }
    __syncthreads();   // sync1: spin done + prior-step xh reads done

    // [D] stage h_t — coalesced sc1 loads (bypass caches, read MALL)
    {
      const float h0 = __hip_atomic_load(&hin[tid], __ATOMIC_RELAXED,
                                         __HIP_MEMORY_SCOPE_AGENT);
      const float h1 = __hip_atomic_load(&hin[tid + 512], __ATOMIC_RELAXED,
                                         __HIP_MEMORY_SCOPE_AGENT);
      const float h2 = __hip_atomic_load(&hin[tid + 1024], __ATOMIC_RELAXED,
                                         __HIP_MEMORY_SCOPE_AGENT);
      const float h3 = __hip_atomic_load(&hin[tid + 1536], __ATOMIC_RELAXED,
                                         __HIP_MEMORY_SCOPE_AGENT);
      xh[hw0] = h0;
      xh[hw1] = h1;
      xh[hw2] = h2;
      xh[hw3] = h3;
    }
    __syncthreads();   // sync2: xh fully staged

    // [F] 192 FMAs against register-resident weights
    float ac0 = 0.f, ac1 = 0.f, ac2 = 0.f, ac3 = 0.f,
          ac4 = 0.f, ac5 = 0.f, ac6 = 0.f, ac7 = 0.f;
    {
      floatx4 v;
      FMAJ(0); FMAJ(1); FMAJ(2); FMAJ(3); FMAJ(4); FMAJ(5);
    }

    // [G] wave reduction (64 lanes -> lane 0) for the 8 row-sums
    WRED(ac0, 0); WRED(ac1, 1); WRED(ac2, 2); WRED(ac3, 3);
    WRED(ac4, 4); WRED(ac5, 5); WRED(ac6, 6); WRED(ac7, 7);
    __syncthreads();   // sync3: partials visible

    // [K] combine partials + gates + state update (rows by threads 0..7)
    if (tid < 8) {
      const int rr = tid;
      const float pi = bl[rr]      + red[0 * 8 + rr] + red[1 * 8 + rr];
      const float pf = bl[8 + rr]  + red[2 * 8 + rr] + red[3 * 8 + rr];
      const float po = bl[16 + rr] + red[4 * 8 + rr] + red[5 * 8 + rr];
      const float pc = bl[24 + rr] + red[6 * 8 + rr] + red[7 * 8 + rr];
      const float iv = 1.f / (1.f + __expf(-pi));
      const float fv = 1.f / (1.f + __expf(-pf));
      const float ov = 1.f / (1.f + __expf(-po));
      const float ct = tanhf(pc);
      const float cn = fv * cl[rr] + iv * ct;
      cl[rr] = cn;
      __hip_atomic_store(&hout[row0 + rr], ov * tanhf(cn), __ATOMIC_RELAXED,
                         __HIP_MEMORY_SCOPE_AGENT);
    }
    if (tid == 0) {
      // release: h stores (lanes 0..7, this wave) acked at coherent point
      __asm__ volatile("s_waitcnt vmcnt(0)" ::: "memory");
      __hip_atomic_store(&epoch[b], (uint32_t)(t + 2), __ATOMIC_RELAXED,
                         __HIP_MEMORY_SCOPE_AGENT);
    }
    // no barrier here: next writes to xh/red are behind sync1+sync2
  }

  if (tid < 8) cbuf[row0 + tid] = cl[tid];
  // final h = h_T is in hbuf[0 .. H_DIM)   (t=4095 odd wrote buffer 0)
}

// ---------------------------------------------------------------------------
// out[0:512] = W2 @ [h; c] + b2   (fp32 in, fp32 out)
// ---------------------------------------------------------------------------
__global__ __launch_bounds__(256)
void final_kernel(const float* __restrict__ W2, const float* __restrict__ b2,
                  const float* __restrict__ hfin, const float* __restrict__ cfin,
                  float* __restrict__ out)
{
  const int wv   = threadIdx.x >> 6;
  const int lane = threadIdx.x & 63;
  const int row  = (blockIdx.x << 2) + wv;
  const float* wr = W2 + (size_t)row * (2 * H_DIM);
  float acc = 0.f;
#pragma unroll 4
  for (int k = lane; k < H_DIM; k += 64) {
    acc = fmaf(wr[k], hfin[k], acc);
    acc = fmaf(wr[H_DIM + k], cfin[k], acc);
  }
#pragma unroll
  for (int off = 32; off > 0; off >>= 1) acc += __shfl_down(acc, off, 64);
  if (lane == 0) out[row] = acc + b2[row];
}

__global__ __launch_bounds__(256)
void copy_h_kernel(const float* __restrict__ hfin, float* __restrict__ out)
{
  const int i = blockIdx.x * 256 + threadIdx.x;
  if (i < H_DIM) out[OUT_DIM + i] = hfin[i];
}

// ---------------------------------------------------------------------------
extern "C" void kernel_launch(void* const* d_in, const int* in_sizes, int n_in,
                              void* d_out, int out_size, void* d_ws, size_t ws_size,
                              hipStream_t stream)
{
  const float* x   = (const float*)d_in[0];
  const float* Wi  = (const float*)d_in[1];
  const float* bi  = (const float*)d_in[2];
  const float* Wf  = (const float*)d_in[3];
  const float* bff = (const float*)d_in[4];
  const float* Wo  = (const float*)d_in[5];
  const float* bo  = (const float*)d_in[6];
  const float* Wc  = (const float*)d_in[7];
  const float* bc  = (const float*)d_in[8];
  const float* W2  = (const float*)d_in[9];
  const float* b2  = (const float*)d_in[10];
  float* out = (float*)d_out;

  // workspace: [hbuf 2*H f32][cbuf H f32][epoch 256 u32]  (~25 KB total)
  char* ws = (char*)d_ws;
  float*    hbuf  = (float*)ws;
  float*    cbuf  = hbuf + 2 * H_DIM;
  uint32_t* epoch = (uint32_t*)(cbuf + H_DIM);

  hipMemsetAsync(epoch, 0, NBLK * sizeof(uint32_t), stream);

  lstm_scan<<<dim3(NBLK), dim3(NTHR), 0, stream>>>(
      Wi, Wf, Wo, Wc, bi, bff, bo, bc, x, hbuf, cbuf, epoch);
  final_kernel<<<dim3(OUT_DIM / 4), 256, 0, stream>>>(W2, b2, hbuf, cbuf, out);
  copy_h_kernel<<<dim3((H_DIM + 255) / 256), 256, 0, stream>>>(hbuf, out);
}